// Round 7
// baseline (13.045 us; speedup 1.0000x reference)
//
#include <hip/hip_runtime.h>

#define NPROPS   32
#define BUCKCAP  1024    // per-(property,label) LDS capacity; expected ~128
#define NTHREADS 1024
#define MARGIN   1.0f

// Per-block partials; every block writes its own slot unconditionally every
// call -> no zero-init required, deterministic under graph replay.
struct Ws {
    double    loss[NPROPS];
    long long pairs[NPROPS];
};

// ---------------------------------------------------------------------------
// Kernel 1: one block (1024 thr, 16 waves) per property.
//  - scan only the pid array vectorized; labels/scores fetched scalar under
//    the sparse match mask (1/32 of elements)
//  - ballot-aggregated LDS scatter (1 atomic per wave-group, prefix via popc)
//  - 2-D pair sweep (8 threads per positive), block reduce, one partial out.
// ---------------------------------------------------------------------------
__global__ __launch_bounds__(NTHREADS)
void fused_kernel(const float* __restrict__ scores,
                  const int*   __restrict__ labels,
                  const int*   __restrict__ pids,
                  Ws* __restrict__ ws, int n) {
    const int p    = blockIdx.x;     // property this block owns
    const int tid  = threadIdx.x;
    const int lane = tid & 63;
    const unsigned long long lanelt = (1ull << lane) - 1ull;

    __shared__ float pos_s[BUCKCAP];
    __shared__ float neg_s[BUCKCAP];
    __shared__ int   cnt[2];         // [0]=#neg, [1]=#pos
    __shared__ float wsum[NTHREADS / 64];

    if (tid < 2) cnt[tid] = 0;
    __syncthreads();

    // ---- scan: vector pid loads, lazy scalar label/score loads ----
    const int4* pid4v = (const int4*)pids;
    const int   nvec  = n >> 2;                  // n % 4 == 0 (8192)
    for (int v = tid; v < nvec; v += NTHREADS) {
        const int4 pd = pid4v[v];
        #pragma unroll
        for (int k = 0; k < 4; ++k) {
            const bool match = ((&pd.x)[k] == p);
            int   lab = 0;
            float sc  = 0.0f;
            if (match) {
                const int i = (v << 2) + k;
                lab = labels[i];
                sc  = scores[i];
            }
            #pragma unroll
            for (int g = 0; g < 2; ++g) {
                const unsigned long long m = __ballot(match && lab == g);
                if (m) {
                    const int leader = __builtin_ctzll(m);
                    int base = 0;
                    if (lane == leader)
                        base = atomicAdd(&cnt[g], __popcll(m));
                    base = __shfl(base, leader, 64);
                    if (match && lab == g) {
                        const int idx = base + __popcll(m & lanelt);
                        if (g) pos_s[idx] = sc; else neg_s[idx] = sc;
                    }
                }
            }
        }
    }
    __syncthreads();

    const int nneg = cnt[0];
    const int npos = cnt[1];

    // ---- pair sweep: 8 threads per positive, j striped by 8 ----
    float acc = 0.0f;
    const int j0 = tid & 7;
    for (int i = tid >> 3; i < npos; i += NTHREADS / 8) {
        const float a = MARGIN - pos_s[i];
        for (int j = j0; j < nneg; j += 8)
            acc += fmaxf(a + neg_s[j], 0.0f);
    }

    // ---- block reduction ----
    #pragma unroll
    for (int off = 32; off > 0; off >>= 1)
        acc += __shfl_down(acc, off);
    if ((tid & 63) == 0) wsum[tid >> 6] = acc;
    __syncthreads();

    if (tid == 0) {
        float s = 0.0f;
        #pragma unroll
        for (int w = 0; w < NTHREADS / 64; ++w) s += wsum[w];
        ws->loss[p]  = (double)s;
        ws->pairs[p] = (long long)npos * (long long)nneg;
    }
}

// ---------------------------------------------------------------------------
// Kernel 2: one wave reduces the 32 partials and writes the mean.
// ---------------------------------------------------------------------------
__global__ __launch_bounds__(64)
void finalize_kernel(const Ws* __restrict__ ws, float* __restrict__ out) {
    const int lane = threadIdx.x;
    double    l = (lane < NPROPS) ? ws->loss[lane]  : 0.0;
    long long c = (lane < NPROPS) ? ws->pairs[lane] : 0;
    #pragma unroll
    for (int off = 16; off > 0; off >>= 1) {   // 32 live values
        l += __shfl_down(l, off);
        c += __shfl_down(c, off);
    }
    if (lane == 0) out[0] = (c == 0) ? 0.0f : (float)(l / (double)c);
}

extern "C" void kernel_launch(void* const* d_in, const int* in_sizes, int n_in,
                              void* d_out, int out_size, void* d_ws, size_t ws_size,
                              hipStream_t stream) {
    const float* scores = (const float*)d_in[0];
    const int*   labels = (const int*)d_in[1];
    const int*   pids   = (const int*)d_in[2];
    const int    n      = in_sizes[0];
    Ws* ws = (Ws*)d_ws;

    fused_kernel<<<NPROPS, NTHREADS, 0, stream>>>(scores, labels, pids, ws, n);
    finalize_kernel<<<1, 64, 0, stream>>>(ws, (float*)d_out);
}